// Round 10
// baseline (115.266 us; speedup 1.0000x reference)
//
#include <hip/hip_runtime.h>

#define NB 4
#define NS 2048
#define ND 1024
#define NH 16
#define NDH 64
#define NR 12
#define NRH 192

typedef __attribute__((ext_vector_type(8))) short bf16x8;
typedef __attribute__((ext_vector_type(4))) float f32x4;

__device__ __forceinline__ unsigned short rnbf(float f) {
  unsigned u = __float_as_uint(f);
  u += 0x7fffu + ((u >> 16) & 1u);
  return (unsigned short)(u >> 16);
}
__device__ __forceinline__ float bf2f(unsigned short h) {
  return __uint_as_float(((unsigned)h) << 16);
}

// v_cvt_pk_bf16_f32: dst[15:0]=bf16(a) RNE, dst[31:16]=bf16(b)
__device__ __forceinline__ unsigned cvtpk(float a, float b) {
  unsigned r;
  asm("v_cvt_pk_bf16_f32 %0, %1, %2" : "=v"(r) : "v"(a), "v"(b));
  return r;
}
__device__ __forceinline__ uint4 pk_hi(float4 u, float4 w) {
  uint4 h;
  h.x = cvtpk(u.x, u.y); h.y = cvtpk(u.z, u.w);
  h.z = cvtpk(w.x, w.y); h.w = cvtpk(w.z, w.w);
  return h;
}
__device__ __forceinline__ unsigned lo2(float a, float b, unsigned hh) {
  float ah = __uint_as_float(hh << 16);
  float bh = __uint_as_float(hh & 0xffff0000u);
  return cvtpk(a - ah, b - bh);
}
__device__ __forceinline__ uint4 pk_lo(float4 u, float4 w, uint4 h) {
  uint4 l;
  l.x = lo2(u.x, u.y, h.x); l.y = lo2(u.z, u.w, h.y);
  l.z = lo2(w.x, w.y, h.z); l.w = lo2(w.z, w.w, h.w);
  return l;
}

__device__ __forceinline__ void gload16(const void* g, void* l) {
  __builtin_amdgcn_global_load_lds(
      (const __attribute__((address_space(1))) unsigned int*)g,
      (__attribute__((address_space(3))) unsigned int*)l, 16, 0, 0);
}

#define MFMA(a, b, c) __builtin_amdgcn_mfma_f32_16x16x32_bf16(a, b, c, 0, 0, 0)

// ---------------------------------------------------------------------------
// Wq_eff[b,h,r,e] = sum_d U[b,h,r,d] * W_Q[h*64+d, e]  -> hi/lo bf16
// ---------------------------------------------------------------------------
__global__ __launch_bounds__(256) void build_wqeff(const float* __restrict__ U,
                                                   const float* __restrict__ WQ,
                                                   unsigned short* __restrict__ wqhi,
                                                   unsigned short* __restrict__ wqlo) {
  int idx = blockIdx.x;
  int hr = idx % (NH * NR);
  int h = hr / NR;
  __shared__ float u[NDH];
  int t = threadIdx.x;
  if (t < NDH) u[t] = U[(size_t)idx * NDH + t];
  __syncthreads();
  int e0 = t * 4;
  float a0 = 0.f, a1 = 0.f, a2 = 0.f, a3 = 0.f;
  const float* wbase = WQ + (size_t)h * NDH * ND + e0;
#pragma unroll 4
  for (int d = 0; d < NDH; ++d) {
    float uv = u[d];
    const float* wr = wbase + (size_t)d * ND;
    a0 += uv * wr[0]; a1 += uv * wr[1]; a2 += uv * wr[2]; a3 += uv * wr[3];
  }
  ushort4 h4, l4;
  h4.x = rnbf(a0); l4.x = rnbf(a0 - bf2f(h4.x));
  h4.y = rnbf(a1); l4.y = rnbf(a1 - bf2f(h4.y));
  h4.z = rnbf(a2); l4.z = rnbf(a2 - bf2f(h4.z));
  h4.w = rnbf(a3); l4.w = rnbf(a3 - bf2f(h4.w));
  *(ushort4*)&wqhi[(size_t)idx * ND + e0] = h4;
  *(ushort4*)&wqlo[(size_t)idx * ND + e0] = l4;
}

// ---------------------------------------------------------------------------
// gemm_tn: C^T-oriented GEMM, BM=16 (1536 blocks -> 6 blocks/CU, 24 waves/CU).
//   out[n][m] = sum_k A[m][k]*B[n][k]; M=2048(s), N=192(rh), K=1024.
// A = fp32 reg-staged to bf16 (pair iff PAIR), swizzled LDS.
// B = bf16 (pair iff PAIR) via global_load_lds, pre-swizzled source.
// Each of 4 waves owns a 16(m) x 16(n) output fragment.
// XCD decode: bijective, m-chunks interleaved across XCDs, the 3 n-blocks of
// one (b,m0) adjacent -> Q/V tile read once per XCD-L2.
// ---------------------------------------------------------------------------
template <bool PAIR>
__global__ __launch_bounds__(256) void gemm_tn(
    const float* __restrict__ Af,
    const unsigned short* __restrict__ Bhi, const unsigned short* __restrict__ Blo,
    unsigned short* __restrict__ C0, unsigned short* __restrict__ C1) {
  constexpr int NBUF = PAIR ? 2 : 1;
  __shared__ unsigned short As[NBUF][16 * 64];
  __shared__ unsigned short Bs[NBUF][64 * 64];
  const int tid = threadIdx.x;
  const int lane = tid & 63;
  const int wid = tid >> 6;

  int lin = blockIdx.x;                  // 0..1535
  int xcd = lin & 7, slot = lin >> 3;    // slot 0..191
  int b = slot / 48;
  int rem = slot % 48;
  int m0 = ((rem / 3) * 8 + xcd) * 16;   // 0..2032
  int n0 = (rem % 3) * 64;

  const float* pA = Af + (size_t)b * NS * ND;
  const unsigned short* pBhi = Bhi + (size_t)b * NRH * ND;
  const unsigned short* pBlo = PAIR ? Blo + (size_t)b * NRH * ND : nullptr;

  const int rsub = lane >> 3;
  const int slotg = (lane & 7) ^ rsub;   // pre-swizzled gload slot
  const int arow = tid >> 4;             // 0..15 (A stage row)
  const int aj = (tid & 15) >> 1;        // A slot 0..7
  const int ah8 = (tid & 1) * 8;         // byte half within 16B slot

  f32x4 acc = (f32x4){0.f, 0.f, 0.f, 0.f};

  for (int k0 = 0; k0 < ND; k0 += 64) {
    // ---- A: fp32 -> bf16 (pair) reg-stage, swizzled ds_write (8B granules)
    {
      const float* asrc = pA + (size_t)(m0 + arow) * ND + k0 + (tid & 15) * 4;
      float4 v = *(const float4*)asrc;
      uint2 h;
      h.x = cvtpk(v.x, v.y); h.y = cvtpk(v.z, v.w);
      char* dst = (char*)&As[0][0] + arow * 128 + ((aj ^ (arow & 7)) << 4) + ah8;
      *(uint2*)dst = h;
      if (PAIR) {
        uint2 l;
        l.x = lo2(v.x, v.y, h.x); l.y = lo2(v.z, v.w, h.y);
        *(uint2*)(dst + 2048) = l;
      }
    }
    // ---- B: bf16 via global_load_lds (pre-swizzled source)
#pragma unroll
    for (int cc = 0; cc < 2; ++cc) {
      int c = wid * 2 + cc;
      int grow = n0 + c * 8 + rsub;
      gload16(&pBhi[(size_t)grow * ND + k0 + slotg * 8], &As[0][0] == nullptr ? nullptr : &Bs[0][c * 512]);
      if (PAIR)
        gload16(&pBlo[(size_t)grow * ND + k0 + slotg * 8], &Bs[NBUF - 1][c * 512]);
    }
    __syncthreads();

#pragma unroll
    for (int kk = 0; kk < 64; kk += 32) {
      int sig = (kk >> 3) + (lane >> 4);
      bf16x8 ah, al, bh, bl;
      {
        int r = lane & 15;
        int off = r * 128 + ((sig ^ (r & 7)) << 4);
        ah = *(const bf16x8*)((const char*)&As[0][0] + off);
        if (PAIR) al = *(const bf16x8*)((const char*)&As[0][0] + 2048 + off);
      }
      {
        int r = wid * 16 + (lane & 15);
        int off = r * 128 + ((sig ^ (r & 7)) << 4);
        bh = *(const bf16x8*)((const char*)&Bs[0][0] + off);
        if (PAIR) bl = *(const bf16x8*)((const char*)&Bs[0][0] + 8192 + off);
      }
      acc = MFMA(ah, bh, acc);
      if (PAIR) {
        acc = MFMA(ah, bl, acc);
        acc = MFMA(al, bh, acc);
      }
    }
    __syncthreads();
  }

  // ---- transposed epilogue: lane's 4 acc values are 4 consecutive m=s
  const int jr = lane >> 4, cl = lane & 15;
  {
    int s = m0 + jr * 4;
    int rh = n0 + wid * 16 + cl;
    int orow = PAIR ? rh : (rh % NR) * NH + rh / NR;
    size_t o = ((size_t)b * NRH + orow) * NS + s;
    ushort4 h4;
    h4.x = rnbf(acc[0]); h4.y = rnbf(acc[1]);
    h4.z = rnbf(acc[2]); h4.w = rnbf(acc[3]);
    *(ushort4*)&C0[o] = h4;
    if (PAIR) {
      ushort4 l4;
      l4.x = rnbf(acc[0] - bf2f(h4.x)); l4.y = rnbf(acc[1] - bf2f(h4.y));
      l4.z = rnbf(acc[2] - bf2f(h4.z)); l4.w = rnbf(acc[3] - bf2f(h4.w));
      *(ushort4*)&C1[o] = l4;
    }
  }
}

// ---------------------------------------------------------------------------
// G2: T1 partials. P[z][m][e] = sum_{s in chunk z} s1[m][s]*K[s][e]
// hi/lo pair; in-kernel K transpose+convert; K fp32 regs prefetched across
// the MFMA phase. XCD decode co-locates all 48 blocks of one (b,split).
// ---------------------------------------------------------------------------
__global__ __launch_bounds__(256) void gemm_g2(
    const unsigned short* __restrict__ Ahi, const unsigned short* __restrict__ Alo,
    const float* __restrict__ Kf, float* __restrict__ P,
    int kchunk, int nz) {
  __shared__ unsigned short As[2][64 * 64];  // hi, lo
  __shared__ unsigned short Bs[2][64 * 64];  // hi, lo
  __shared__ float tbuf[64 * 68];
  const int tid = threadIdx.x;
  const int lane = tid & 63;
  const int wid = tid >> 6;
  const int wm = wid >> 1, wn = wid & 1;

  int lin = blockIdx.x;
  int bz, m_idx, n_idx;
  if (nz == 16) {
    int xcd = lin & 7, slot = lin >> 3;
    bz = xcd + 8 * (slot / 48);
    int rem = slot % 48;
    m_idx = rem / 16; n_idx = rem % 16;
  } else {
    bz = lin / 48;
    int rem = lin % 48;
    m_idx = rem / 16; n_idx = rem % 16;
  }
  const int m0 = m_idx * 64, n0 = n_idx * 64;
  const int b = bz % NB;
  const int kbeg = (bz / NB) * kchunk;
  const unsigned short* pAhi = Ahi + (size_t)b * NRH * NS;
  const unsigned short* pAlo = Alo + (size_t)b * NRH * NS;
  const float* pK = Kf + (size_t)b * NS * ND;

  const int rsub = lane >> 3;
  const int slotg = (lane & 7) ^ rsub;
  const int sr = tid >> 2;
  const int eg = (tid & 3) * 16;

  f32x4 acc[2][2];
#pragma unroll
  for (int i = 0; i < 2; ++i)
#pragma unroll
    for (int j = 0; j < 2; ++j) acc[i][j] = (f32x4){0.f, 0.f, 0.f, 0.f};

  float4 kr0, kr1, kr2, kr3;
  {
    const float* ksrc = pK + (size_t)(kbeg + sr) * ND + n0 + eg;
    kr0 = *(const float4*)(ksrc + 0);
    kr1 = *(const float4*)(ksrc + 4);
    kr2 = *(const float4*)(ksrc + 8);
    kr3 = *(const float4*)(ksrc + 12);
  }

  for (int k0 = kbeg; k0 < kbeg + kchunk; k0 += 64) {
#pragma unroll
    for (int cc = 0; cc < 2; ++cc) {
      int c = wid * 2 + cc;
      int grow = m0 + c * 8 + rsub;
      gload16(&pAhi[(size_t)grow * NS + k0 + slotg * 8], &As[0][c * 512]);
      gload16(&pAlo[(size_t)grow * NS + k0 + slotg * 8], &As[1][c * 512]);
    }
    {
      float* td = &tbuf[sr * 68 + eg];
      *(float4*)(td + 0) = kr0;
      *(float4*)(td + 4) = kr1;
      *(float4*)(td + 8) = kr2;
      *(float4*)(td + 12) = kr3;
    }
    __syncthreads();
    {
      const int e = tid & 63;
      const int sg = (tid >> 6) * 16;
      float v[16];
#pragma unroll
      for (int i = 0; i < 16; ++i) v[i] = tbuf[(sg + i) * 68 + e];
      float4 u0 = {v[0], v[1], v[2], v[3]},   w0 = {v[4], v[5], v[6], v[7]};
      float4 u1 = {v[8], v[9], v[10], v[11]}, w1 = {v[12], v[13], v[14], v[15]};
      uint4 h0 = pk_hi(u0, w0), h1 = pk_hi(u1, w1);
      int j0 = sg >> 3;
      char* dbase = (char*)&Bs[0][0] + e * 128;
      *(uint4*)(dbase + (((j0 + 0) ^ (e & 7)) << 4)) = h0;
      *(uint4*)(dbase + (((j0 + 1) ^ (e & 7)) << 4)) = h1;
      char* dlo = (char*)&Bs[1][0] + e * 128;
      *(uint4*)(dlo + (((j0 + 0) ^ (e & 7)) << 4)) = pk_lo(u0, w0, h0);
      *(uint4*)(dlo + (((j0 + 1) ^ (e & 7)) << 4)) = pk_lo(u1, w1, h1);
    }
    __syncthreads();
    if (k0 + 64 < kbeg + kchunk) {
      const float* ksrc = pK + (size_t)(k0 + 64 + sr) * ND + n0 + eg;
      kr0 = *(const float4*)(ksrc + 0);
      kr1 = *(const float4*)(ksrc + 4);
      kr2 = *(const float4*)(ksrc + 8);
      kr3 = *(const float4*)(ksrc + 12);
    }
#pragma unroll
    for (int kk = 0; kk < 64; kk += 32) {
      int sig = (kk >> 3) + (lane >> 4);
      bf16x8 ah[2], al[2], bh[2], bl[2];
#pragma unroll
      for (int fm = 0; fm < 2; ++fm) {
        int r = wm * 32 + fm * 16 + (lane & 15);
        int off = r * 128 + ((sig ^ (r & 7)) << 4);
        ah[fm] = *(const bf16x8*)((const char*)&As[0][0] + off);
        al[fm] = *(const bf16x8*)((const char*)&As[1][0] + off);
      }
#pragma unroll
      for (int fn = 0; fn < 2; ++fn) {
        int r = wn * 32 + fn * 16 + (lane & 15);
        int off = r * 128 + ((sig ^ (r & 7)) << 4);
        bh[fn] = *(const bf16x8*)((const char*)&Bs[0][0] + off);
        bl[fn] = *(const bf16x8*)((const char*)&Bs[1][0] + off);
      }
#pragma unroll
      for (int fm = 0; fm < 2; ++fm)
#pragma unroll
        for (int fn = 0; fn < 2; ++fn) {
          acc[fm][fn] = MFMA(ah[fm], bh[fn], acc[fm][fn]);
          acc[fm][fn] = MFMA(ah[fm], bl[fn], acc[fm][fn]);
          acc[fm][fn] = MFMA(al[fm], bh[fn], acc[fm][fn]);
        }
    }
    __syncthreads();
  }

  const int jr = lane >> 4, cl = lane & 15;
  float* pc = P + (size_t)bz * NRH * ND;
#pragma unroll
  for (int fm = 0; fm < 2; ++fm)
#pragma unroll
    for (int fn = 0; fn < 2; ++fn) {
      f32x4 v = acc[fm][fn];
      int gcol = n0 + wn * 32 + fn * 16 + cl;
#pragma unroll
      for (int j = 0; j < 4; ++j) {
        int m = m0 + wm * 32 + fm * 16 + jr * 4 + j;
        pc[(size_t)m * ND + gcol] = v[j];
      }
    }
}

// ---------------------------------------------------------------------------
// G4: lin[m][n] = sum_k ctx[m][k]*WL[n][k]; M=1536 N=1024 K=1024.
// BM=32 -> 768 blocks. A=ctx bf16 gload; B=WL fp32 reg-staged to bf16.
// ---------------------------------------------------------------------------
__global__ __launch_bounds__(256) void gemm_g4(
    const unsigned short* __restrict__ A, const float* __restrict__ Bf,
    float* __restrict__ lin) {
  __shared__ unsigned short As[32 * 64];
  __shared__ unsigned short Bs[64 * 64];
  const int tid = threadIdx.x;
  const int lane = tid & 63;
  const int wid = tid >> 6;
  const int wm = wid >> 1, wn = wid & 1;
  const int m0 = (blockIdx.x >> 4) * 32, n0 = (blockIdx.x & 15) * 64;
  const int rsub = lane >> 3;
  const int slotg = (lane & 7) ^ rsub;
  const int brow = tid >> 2;
  const int jbase = (tid & 3) * 2;

  f32x4 acc[2];
  acc[0] = (f32x4){0.f, 0.f, 0.f, 0.f};
  acc[1] = (f32x4){0.f, 0.f, 0.f, 0.f};

  for (int k0 = 0; k0 < ND; k0 += 64) {
    // A: one gload16 per thread (wave covers 8 rows x 8 slots)
    gload16(&A[(size_t)(m0 + wid * 8 + rsub) * ND + k0 + slotg * 8],
            &As[wid * 512]);
    // B: fp32 -> bf16 reg-stage, swizzled
    {
      const float* bsrc = Bf + (size_t)(n0 + brow) * ND + k0 + jbase * 8;
      float4 u0 = *(const float4*)(bsrc + 0), v0 = *(const float4*)(bsrc + 4);
      float4 u1 = *(const float4*)(bsrc + 8), v1 = *(const float4*)(bsrc + 12);
      char* dbase = (char*)&Bs[0] + brow * 128;
      *(uint4*)(dbase + (((jbase + 0) ^ (brow & 7)) << 4)) = pk_hi(u0, v0);
      *(uint4*)(dbase + (((jbase + 1) ^ (brow & 7)) << 4)) = pk_hi(u1, v1);
    }
    __syncthreads();

#pragma unroll
    for (int kk = 0; kk < 64; kk += 32) {
      int sig = (kk >> 3) + (lane >> 4);
      bf16x8 ah, bh[2];
      {
        int r = wm * 16 + (lane & 15);
        int off = r * 128 + ((sig ^ (r & 7)) << 4);
        ah = *(const bf16x8*)((const char*)&As[0] + off);
      }
#pragma unroll
      for (int fn = 0; fn < 2; ++fn) {
        int r = wn * 32 + fn * 16 + (lane & 15);
        int off = r * 128 + ((sig ^ (r & 7)) << 4);
        bh[fn] = *(const bf16x8*)((const char*)&Bs[0] + off);
      }
#pragma unroll
      for (int fn = 0; fn < 2; ++fn) acc[fn] = MFMA(ah, bh[fn], acc[fn]);
    }
    __syncthreads();
  }

  const int jr = lane >> 4, cl = lane & 15;
#pragma unroll
  for (int fn = 0; fn < 2; ++fn) {
    f32x4 v = acc[fn];
    int gcol = n0 + wn * 32 + fn * 16 + cl;
#pragma unroll
    for (int j = 0; j < 4; ++j) {
      int m = m0 + wm * 16 + jr * 4 + j;
      lin[(size_t)m * ND + gcol] = v[j];
    }
  }
}

// ---------------------------------------------------------------------------
// bias + LayerNorm -> out
// ---------------------------------------------------------------------------
__global__ __launch_bounds__(256) void bias_ln(const float* __restrict__ lin,
                                               const float* __restrict__ bias,
                                               const float* __restrict__ gamma,
                                               const float* __restrict__ beta,
                                               float* __restrict__ out) {
  int row = blockIdx.x;
  int t = threadIdx.x;
  float4 a = ((const float4*)(lin + (size_t)row * ND))[t];
  float4 bv = ((const float4*)bias)[t];
  a.x += bv.x; a.y += bv.y; a.z += bv.z; a.w += bv.w;

  float s = a.x + a.y + a.z + a.w;
  float ss = a.x * a.x + a.y * a.y + a.z * a.z + a.w * a.w;
#pragma unroll
  for (int off = 32; off > 0; off >>= 1) {
    s += __shfl_xor(s, off);
    ss += __shfl_xor(ss, off);
  }
  __shared__ float red[8];
  int wave = t >> 6, lane = t & 63;
  if (lane == 0) { red[wave] = s; red[4 + wave] = ss; }
  __syncthreads();
  s = red[0] + red[1] + red[2] + red[3];
  ss = red[4] + red[5] + red[6] + red[7];
  float mu = s * (1.0f / ND);
  float var = ss * (1.0f / ND) - mu * mu;
  float inv = rsqrtf(var + 1e-6f);
  float4 g = ((const float4*)gamma)[t];
  float4 be = ((const float4*)beta)[t];
  float4 o;
  o.x = (a.x - mu) * inv * g.x + be.x;
  o.y = (a.y - mu) * inv * g.y + be.y;
  o.z = (a.z - mu) * inv * g.z + be.z;
  o.w = (a.w - mu) * inv * g.w + be.w;
  ((float4*)(out + (size_t)row * ND))[t] = o;
}

// ---------------------------------------------------------------------------
// sm_k: one block per (b,h,r). Sums G2's split partials inline.
// ---------------------------------------------------------------------------
__global__ __launch_bounds__(256) void sm_k(const float* __restrict__ P,
                                            int nsplit,
                                            const float* __restrict__ WK,
                                            const float* __restrict__ WV,
                                            unsigned short* __restrict__ A2) {
  int x = blockIdx.x;
  int xcd = x & 7, within = x >> 3;
  int h = xcd + 8 * (within & 1);
  int rb = within >> 1;
  int r = rb >> 2, b = rb & 3;
  int idx = (b * NH + h) * NR + r;
  int rh = h * NR + r;

  const int t = threadIdx.x;
  const int lane = t & 63, wv = t >> 6;
  __shared__ float t1s[ND];
  __shared__ float s2s[NDH];
  __shared__ float attns[NDH];

  {
    const size_t sstride = (size_t)NB * NRH * ND;
    const float* base = P + ((size_t)b * NRH + rh) * ND;
    float4 a = ((const float4*)base)[t];
    for (int s = 1; s < nsplit; ++s) {
      float4 v = ((const float4*)(base + (size_t)s * sstride))[t];
      a.x += v.x; a.y += v.y; a.z += v.z; a.w += v.w;
    }
    ((float4*)t1s)[t] = a;
  }
  __syncthreads();

  for (int j = 0; j < 16; ++j) {
    int d = wv * 16 + j;
    const float* row = WK + (size_t)(h * NDH + d) * ND;
    float acc = 0.f;
#pragma unroll
    for (int i = 0; i < 16; ++i) acc += row[lane + i * 64] * t1s[lane + i * 64];
#pragma unroll
    for (int off = 32; off > 0; off >>= 1) acc += __shfl_xor(acc, off);
    if (lane == 0) s2s[d] = acc;
  }
  __syncthreads();

  if (t < NDH) {
    float s2 = s2s[t];
    float m = s2;
#pragma unroll
    for (int off = 32; off > 0; off >>= 1) m = fmaxf(m, __shfl_xor(m, off));
    float e = __expf(s2 - m);
    float sum = e;
#pragma unroll
    for (int off = 32; off > 0; off >>= 1) sum += __shfl_xor(sum, off);
    attns[t] = e / sum;
  }
  __syncthreads();

  {
    int e0 = t * 4;
    const float* wvp = WV + (size_t)h * NDH * ND + e0;
    float a0 = 0.f, a1 = 0.f, a2 = 0.f, a3 = 0.f;
#pragma unroll 4
    for (int dd = 0; dd < NDH; ++dd) {
      float4 wvv = *(const float4*)&wvp[(size_t)dd * ND];
      float a = attns[dd];
      a0 += a * wvv.x; a1 += a * wvv.y; a2 += a * wvv.z; a3 += a * wvv.w;
    }
    ushort4 o;
    o.x = rnbf(a0); o.y = rnbf(a1); o.z = rnbf(a2); o.w = rnbf(a3);
    *(ushort4*)&A2[(size_t)idx * ND + e0] = o;
  }
}

// ---------------------------------------------------------------------------
extern "C" void kernel_launch(void* const* d_in, const int* in_sizes, int n_in,
                              void* d_out, int out_size, void* d_ws, size_t ws_size,
                              hipStream_t stream) {
  const float* Q = (const float*)d_in[0];
  const float* K = (const float*)d_in[1];
  const float* V = (const float*)d_in[2];
  const float* U = (const float*)d_in[3];
  const float* WQ = (const float*)d_in[4];
  const float* WK = (const float*)d_in[5];
  const float* WV = (const float*)d_in[6];
  const float* WL = (const float*)d_in[7];
  const float* bl = (const float*)d_in[8];
  const float* ga = (const float*)d_in[9];
  const float* be = (const float*)d_in[10];
  float* out = (float*)d_out;
  char* w = (char*)d_ws;

  unsigned short* wqhi = (unsigned short*)w;
  unsigned short* wqlo = (unsigned short*)(w + 1572864);
  unsigned short* A2b = wqhi;  // reuse after G1t
  unsigned short* s1hi = (unsigned short*)(w + 3145728);
  unsigned short* s1lo = (unsigned short*)(w + 6291456);
  unsigned short* ctxb = (unsigned short*)(w + 9437184);
  float* lin = (float*)(w + 12582912);
  float* P = (float*)(w + 18874368);

  size_t avail = ws_size > 18874368 ? ws_size - 18874368 : 0;
  int sG2 = 1;
  while (sG2 * 2 <= 4 && 3145728ull * (size_t)(sG2 * 2) <= avail) sG2 *= 2;

  build_wqeff<<<NB * NH * NR, 256, 0, stream>>>(U, WQ, wqhi, wqlo);

  // G1t: s1^T, BM=16, 1536 blocks, XCD-decoded.
  gemm_tn<true><<<1536, 256, 0, stream>>>(Q, wqhi, wqlo, s1hi, s1lo);

  // G2: split-K partials, fused K transpose+convert, K-reg prefetch.
  gemm_g2<<<48 * NB * sG2, 256, 0, stream>>>(s1hi, s1lo, K, P, 2048 / sG2,
                                             NB * sG2);

  // s2 -> softmax -> A2 (sums G2 partials inline)
  sm_k<<<NB * NH * NR, 256, 0, stream>>>(P, sG2, WK, WV, A2b);

  // G3t: ctx^T, BM=16, 1536 blocks, XCD-decoded.
  gemm_tn<false><<<1536, 256, 0, stream>>>(V, A2b, nullptr, ctxb, nullptr);

  // G4: lin = ctx @ WL^T, BM=32, 768 blocks.
  gemm_g4<<<768, 256, 0, stream>>>(ctxb, WL, lin);

  // bias + LayerNorm -> out
  bias_ln<<<NB * 384, 256, 0, stream>>>(lin, bl, ga, be, out);
}